// Round 1
// baseline (561.357 us; speedup 1.0000x reference)
//
#include <hip/hip_runtime.h>

#define CH 64

__device__ __forceinline__ float frcp(float x) { return __builtin_amdgcn_rcpf(x); }

// tanh via hardware exp + rcp: tanh(x) = 1 - 2/(exp(2x)+1)
__device__ __forceinline__ float ftanh(float x) {
    float e = __expf(2.0f * x);
    return 1.0f - 2.0f * frcp(e + 1.0f);
}

__device__ __forceinline__ float fsigm(float x) {
    return frcp(1.0f + __expf(-x));
}

// numerically stable softplus (setup only, once per thread)
__device__ __forceinline__ float softplus_f(float x) {
    float ax = fabsf(x);
    return fmaxf(x, 0.0f) + log1pf(__expf(-ax));
}

__device__ __forceinline__ float chain(float x,
    const float* w0, const float* B0, const float* T0,
    const float* w1, const float* B1, const float* T1,
    const float* w2, const float* B2, const float* T2,
    const float* w3, float B3, float T3)
{
    float l[3], t[3];
#pragma unroll
    for (int i = 0; i < 3; i++) {
        float z = fmaf(w0[i], x, B0[i]);
        l[i] = fmaf(T0[i], ftanh(z), z);
    }
#pragma unroll
    for (int i = 0; i < 3; i++) {
        float z = B1[i];
#pragma unroll
        for (int j = 0; j < 3; j++) z = fmaf(w1[i * 3 + j], l[j], z);
        t[i] = fmaf(T1[i], ftanh(z), z);
    }
#pragma unroll
    for (int i = 0; i < 3; i++) {
        float z = B2[i];
#pragma unroll
        for (int j = 0; j < 3; j++) z = fmaf(w2[i * 3 + j], t[j], z);
        l[i] = fmaf(T2[i], ftanh(z), z);
    }
    float z = B3;
#pragma unroll
    for (int j = 0; j < 3; j++) z = fmaf(w3[j], l[j], z);
    return fmaf(T3, ftanh(z), z);
}

__global__ __launch_bounds__(256) void eb_kernel(
    const float* __restrict__ in, const float* __restrict__ noise,
    const float* __restrict__ m0, const float* __restrict__ b0, const float* __restrict__ f0,
    const float* __restrict__ m1, const float* __restrict__ b1, const float* __restrict__ f1,
    const float* __restrict__ m2, const float* __restrict__ b2, const float* __restrict__ f2,
    const float* __restrict__ m3, const float* __restrict__ b3, const float* __restrict__ f3,
    float* __restrict__ out, int total)
{
    const int tid = blockIdx.x * blockDim.x + threadIdx.x;
    const int c = tid & (CH - 1);   // total threads multiple of 64 -> channel fixed per thread

    // per-channel parameters -> registers (softplus / tanh applied once)
    float w0[3], B0[3], T0[3];
    float w1[9], B1[3], T1[3];
    float w2[9], B2[3], T2[3];
    float w3[3], B3, T3;
#pragma unroll
    for (int i = 0; i < 3; i++) {
        w0[i] = softplus_f(m0[c * 3 + i]);
        B0[i] = b0[c * 3 + i];
        T0[i] = tanhf(f0[c * 3 + i]);
        B1[i] = b1[c * 3 + i];
        T1[i] = tanhf(f1[c * 3 + i]);
        B2[i] = b2[c * 3 + i];
        T2[i] = tanhf(f2[c * 3 + i]);
        w3[i] = softplus_f(m3[c * 3 + i]);
    }
#pragma unroll
    for (int i = 0; i < 9; i++) {
        w1[i] = softplus_f(m1[c * 9 + i]);
        w2[i] = softplus_f(m2[c * 9 + i]);
    }
    B3 = b3[c];
    T3 = tanhf(f3[c]);

    const int stride = gridDim.x * blockDim.x;
    for (int idx = tid; idx < total; idx += stride) {
        float v = in[idx] + noise[idx];
        out[idx] = v;

        float lo = chain(v - 0.5f, w0, B0, T0, w1, B1, T1, w2, B2, T2, w3, B3, T3);
        float up = chain(v + 0.5f, w0, B0, T0, w1, B1, T1, w2, B2, T2, w3, B3, T3);

        float sm = lo + up;
        float s = (sm < 0.0f) ? 1.0f : ((sm > 0.0f) ? -1.0f : 0.0f);
        float like = fabsf(fsigm(s * up) - fsigm(s * lo));
        like = fmaxf(like, 1e-9f);
        out[total + idx] = like;
    }
}

extern "C" void kernel_launch(void* const* d_in, const int* in_sizes, int n_in,
                              void* d_out, int out_size, void* d_ws, size_t ws_size,
                              hipStream_t stream) {
    // setup_inputs() dict order: inputs, noise, m0,b0,f0, m1,b1,f1, m2,b2,f2, m3,b3,f3
    const float* in    = (const float*)d_in[0];
    const float* noise = (const float*)d_in[1];
    const float* m0 = (const float*)d_in[2];
    const float* b0 = (const float*)d_in[3];
    const float* f0 = (const float*)d_in[4];
    const float* m1 = (const float*)d_in[5];
    const float* b1 = (const float*)d_in[6];
    const float* f1 = (const float*)d_in[7];
    const float* m2 = (const float*)d_in[8];
    const float* b2 = (const float*)d_in[9];
    const float* f2 = (const float*)d_in[10];
    const float* m3 = (const float*)d_in[11];
    const float* b3 = (const float*)d_in[12];
    const float* f3 = (const float*)d_in[13];
    float* out = (float*)d_out;

    const int total = in_sizes[0];   // N*C = 32,000,000
    const int threads = 256;
    const int blocks = 2048;         // 8 blocks/CU worth of work; ~61 iters/thread

    eb_kernel<<<blocks, threads, 0, stream>>>(in, noise,
        m0, b0, f0, m1, b1, f1, m2, b2, f2, m3, b3, f3,
        out, total);
}

// Round 2
// 460.449 us; speedup vs baseline: 1.2192x; 1.2192x over previous
//
#include <hip/hip_runtime.h>

#define CH 64

__device__ __forceinline__ float frcp(float x) { return __builtin_amdgcn_rcpf(x); }

// tanh via hardware exp + rcp (general fallback path only)
__device__ __forceinline__ float ftanh(float x) {
    float e = __expf(2.0f * x);
    return 1.0f - 2.0f * frcp(e + 1.0f);
}

// numerically stable softplus (setup only, once per thread)
__device__ __forceinline__ float softplus_f(float x) {
    float ax = fabsf(x);
    return fmaxf(x, 0.0f) + log1pf(__expf(-ax));
}

// ---------- general path (gates may be nonzero): scalar chain with tanh ----------
__device__ __forceinline__ float chain_gen(float x,
    const float* w0, const float* B0, const float* T0,
    const float* w1, const float* B1, const float* T1,
    const float* w2, const float* B2, const float* T2,
    const float* w3, float B3, float T3)
{
    float l[3], t[3];
#pragma unroll
    for (int i = 0; i < 3; i++) {
        float z = fmaf(w0[i], x, B0[i]);
        l[i] = fmaf(T0[i], ftanh(z), z);
    }
#pragma unroll
    for (int i = 0; i < 3; i++) {
        float z = B1[i];
#pragma unroll
        for (int j = 0; j < 3; j++) z = fmaf(w1[i * 3 + j], l[j], z);
        t[i] = fmaf(T1[i], ftanh(z), z);
    }
#pragma unroll
    for (int i = 0; i < 3; i++) {
        float z = B2[i];
#pragma unroll
        for (int j = 0; j < 3; j++) z = fmaf(w2[i * 3 + j], t[j], z);
        l[i] = fmaf(T2[i], ftanh(z), z);
    }
    float z = B3;
#pragma unroll
    for (int j = 0; j < 3; j++) z = fmaf(w3[j], l[j], z);
    return fmaf(T3, ftanh(z), z);
}

// ---------- fast path (all gates zero): lo/up chains as packed float2 ----------
__device__ __forceinline__ float2 chain2_nogate(float xl, float xu,
    const float* w0, const float* B0,
    const float* w1, const float* B1,
    const float* w2, const float* B2,
    const float* w3, float B3)
{
    float lx[3], ly[3], tx[3], ty[3];
#pragma unroll
    for (int i = 0; i < 3; i++) {
        lx[i] = fmaf(w0[i], xl, B0[i]);
        ly[i] = fmaf(w0[i], xu, B0[i]);
    }
#pragma unroll
    for (int i = 0; i < 3; i++) {
        float zx = B1[i], zy = B1[i];
#pragma unroll
        for (int j = 0; j < 3; j++) {
            zx = fmaf(w1[i * 3 + j], lx[j], zx);
            zy = fmaf(w1[i * 3 + j], ly[j], zy);
        }
        tx[i] = zx; ty[i] = zy;
    }
#pragma unroll
    for (int i = 0; i < 3; i++) {
        float zx = B2[i], zy = B2[i];
#pragma unroll
        for (int j = 0; j < 3; j++) {
            zx = fmaf(w2[i * 3 + j], tx[j], zx);
            zy = fmaf(w2[i * 3 + j], ty[j], zy);
        }
        lx[i] = zx; ly[i] = zy;
    }
    float zx = B3, zy = B3;
#pragma unroll
    for (int j = 0; j < 3; j++) {
        zx = fmaf(w3[j], lx[j], zx);
        zy = fmaf(w3[j], ly[j], zy);
    }
    return make_float2(zx, zy);
}

// likelihood = sigmoid(up) - sigmoid(lo), up >= lo, via single rcp:
//   a=e^{-up}, b=e^{-lo}:  (b-a) / ((1+a)(1+b))
__device__ __forceinline__ float likelihood_f(float lo, float up) {
    lo = fminf(fmaxf(lo, -40.0f), 40.0f);
    up = fminf(fmaxf(up, -40.0f), 40.0f);
    float a = __expf(-up);
    float b = __expf(-lo);
    float num = b - a;
    float den = fmaf(a, b, a) + b + 1.0f;   // (1+a)(1+b) = 1 + a + b + ab
    float like = fabsf(num * frcp(den));
    return fmaxf(like, 1e-9f);
}

__global__ __launch_bounds__(256) void eb_kernel(
    const float* __restrict__ in, const float* __restrict__ noise,
    const float* __restrict__ m0, const float* __restrict__ b0, const float* __restrict__ f0,
    const float* __restrict__ m1, const float* __restrict__ b1, const float* __restrict__ f1,
    const float* __restrict__ m2, const float* __restrict__ b2, const float* __restrict__ f2,
    const float* __restrict__ m3, const float* __restrict__ b3, const float* __restrict__ f3,
    float* __restrict__ out, int total)
{
    const int tid = blockIdx.x * blockDim.x + threadIdx.x;
    const int c = tid & (CH - 1);   // total threads multiple of 64 -> channel fixed per thread

    // per-channel parameters -> registers (softplus / tanh applied once per thread)
    float w0[3], B0[3], T0[3];
    float w1[9], B1[3], T1[3];
    float w2[9], B2[3], T2[3];
    float w3[3], B3, T3;
#pragma unroll
    for (int i = 0; i < 3; i++) {
        w0[i] = softplus_f(m0[c * 3 + i]);
        B0[i] = b0[c * 3 + i];
        T0[i] = tanhf(f0[c * 3 + i]);
        B1[i] = b1[c * 3 + i];
        T1[i] = tanhf(f1[c * 3 + i]);
        B2[i] = b2[c * 3 + i];
        T2[i] = tanhf(f2[c * 3 + i]);
        w3[i] = softplus_f(m3[c * 3 + i]);
    }
#pragma unroll
    for (int i = 0; i < 9; i++) {
        w1[i] = softplus_f(m1[c * 9 + i]);
        w2[i] = softplus_f(m2[c * 9 + i]);
    }
    B3 = b3[c];
    T3 = tanhf(f3[c]);

    // wave-uniform fast-path check: tanh gates all zero -> gate terms vanish
    bool gated = (T3 != 0.0f);
#pragma unroll
    for (int i = 0; i < 3; i++)
        gated = gated || (T0[i] != 0.0f) || (T1[i] != 0.0f) || (T2[i] != 0.0f);

    const int stride = gridDim.x * blockDim.x;

    if (!gated) {
        for (int idx = tid; idx < total; idx += stride) {
            float v = in[idx] + noise[idx];
            out[idx] = v;
            float2 r = chain2_nogate(v - 0.5f, v + 0.5f,
                                     w0, B0, w1, B1, w2, B2, w3, B3);
            out[total + idx] = likelihood_f(r.x, r.y);
        }
    } else {
        for (int idx = tid; idx < total; idx += stride) {
            float v = in[idx] + noise[idx];
            out[idx] = v;
            float lo = chain_gen(v - 0.5f, w0, B0, T0, w1, B1, T1, w2, B2, T2, w3, B3, T3);
            float up = chain_gen(v + 0.5f, w0, B0, T0, w1, B1, T1, w2, B2, T2, w3, B3, T3);
            out[total + idx] = likelihood_f(lo, up);
        }
    }
}

extern "C" void kernel_launch(void* const* d_in, const int* in_sizes, int n_in,
                              void* d_out, int out_size, void* d_ws, size_t ws_size,
                              hipStream_t stream) {
    // setup_inputs() dict order: inputs, noise, m0,b0,f0, m1,b1,f1, m2,b2,f2, m3,b3,f3
    const float* in    = (const float*)d_in[0];
    const float* noise = (const float*)d_in[1];
    const float* m0 = (const float*)d_in[2];
    const float* b0 = (const float*)d_in[3];
    const float* f0 = (const float*)d_in[4];
    const float* m1 = (const float*)d_in[5];
    const float* b1 = (const float*)d_in[6];
    const float* f1 = (const float*)d_in[7];
    const float* m2 = (const float*)d_in[8];
    const float* b2 = (const float*)d_in[9];
    const float* f2 = (const float*)d_in[10];
    const float* m3 = (const float*)d_in[11];
    const float* b3 = (const float*)d_in[12];
    const float* f3 = (const float*)d_in[13];
    float* out = (float*)d_out;

    const int total = in_sizes[0];   // N*C = 32,000,000
    const int threads = 256;
    const int blocks = 2048;

    eb_kernel<<<blocks, threads, 0, stream>>>(in, noise,
        m0, b0, f0, m1, b1, f1, m2, b2, f2, m3, b3, f3,
        out, total);
}

// Round 3
// 452.967 us; speedup vs baseline: 1.2393x; 1.0165x over previous
//
#include <hip/hip_runtime.h>

#define CH 64

__device__ __forceinline__ float frcp(float x) { return __builtin_amdgcn_rcpf(x); }

// tanh via hardware exp + rcp (general fallback path only)
__device__ __forceinline__ float ftanh(float x) {
    float e = __expf(2.0f * x);
    return 1.0f - 2.0f * frcp(e + 1.0f);
}

// numerically stable softplus (setup only)
__device__ __forceinline__ float softplus_f(float x) {
    float ax = fabsf(x);
    return fmaxf(x, 0.0f) + log1pf(__expf(-ax));
}

// ---------- general path (gates may be nonzero): scalar chain with tanh ----------
__device__ __forceinline__ float chain_gen(float x,
    const float* w0, const float* B0, const float* T0,
    const float* w1, const float* B1, const float* T1,
    const float* w2, const float* B2, const float* T2,
    const float* w3, float B3, float T3)
{
    float l[3], t[3];
#pragma unroll
    for (int i = 0; i < 3; i++) {
        float z = fmaf(w0[i], x, B0[i]);
        l[i] = fmaf(T0[i], ftanh(z), z);
    }
#pragma unroll
    for (int i = 0; i < 3; i++) {
        float z = B1[i];
#pragma unroll
        for (int j = 0; j < 3; j++) z = fmaf(w1[i * 3 + j], l[j], z);
        t[i] = fmaf(T1[i], ftanh(z), z);
    }
#pragma unroll
    for (int i = 0; i < 3; i++) {
        float z = B2[i];
#pragma unroll
        for (int j = 0; j < 3; j++) z = fmaf(w2[i * 3 + j], t[j], z);
        l[i] = fmaf(T2[i], ftanh(z), z);
    }
    float z = B3;
#pragma unroll
    for (int j = 0; j < 3; j++) z = fmaf(w3[j], l[j], z);
    return fmaf(T3, ftanh(z), z);
}

// likelihood = sigmoid(up) - sigmoid(lo) (monotone chain -> up > lo), 1 rcp
__device__ __forceinline__ float likelihood_f(float lo, float up) {
    lo = fminf(fmaxf(lo, -30.0f), 30.0f);
    up = fminf(fmaxf(up, -30.0f), 30.0f);
    float a = __expf(-up);
    float b = __expf(-lo);
    float num = b - a;
    float den = fmaf(a, b, a) + b + 1.0f;
    float like = fabsf(num * frcp(den));
    return fmaxf(like, 1e-9f);
}

__global__ __launch_bounds__(256) void eb_kernel(
    const float* __restrict__ in, const float* __restrict__ noise,
    const float* __restrict__ m0, const float* __restrict__ b0, const float* __restrict__ f0,
    const float* __restrict__ m1, const float* __restrict__ b1, const float* __restrict__ f1,
    const float* __restrict__ m2, const float* __restrict__ b2, const float* __restrict__ f2,
    const float* __restrict__ m3, const float* __restrict__ b3, const float* __restrict__ f3,
    float* __restrict__ out, int total)
{
    __shared__ float sA[CH];    // linear coefficient per channel
    __shared__ float sDm[CH];   // D - 0.5*A  (constant term of the LOWER chain)
    __shared__ float sEA[CH];   // exp(-A)

    const int t = threadIdx.x;
    int localGate = 0;

    if (t < CH) {
        const int c = t;
        // per-channel params
        float w0[3], B0[3], w1[9], B1[3], w2[9], B2[3], w3[3];
#pragma unroll
        for (int i = 0; i < 3; i++) {
            w0[i] = softplus_f(m0[c * 3 + i]);
            B0[i] = b0[c * 3 + i];
            B1[i] = b1[c * 3 + i];
            B2[i] = b2[c * 3 + i];
            w3[i] = softplus_f(m3[c * 3 + i]);
        }
#pragma unroll
        for (int i = 0; i < 9; i++) {
            w1[i] = softplus_f(m1[c * 9 + i]);
            w2[i] = softplus_f(m2[c * 9 + i]);
        }
        float B3 = b3[c];

        // gate check (tanh(f)==0 iff f==0 in fp32 for |f|>=denorm; use f directly)
#pragma unroll
        for (int i = 0; i < 3; i++)
            localGate |= (f0[c * 3 + i] != 0.0f) | (f1[c * 3 + i] != 0.0f) | (f2[c * 3 + i] != 0.0f);
        localGate |= (f3[c] != 0.0f);

        // compose the 4 linear layers: y = A*x + D
        float a0[3], d0[3], a1[3], d1[3], a2[3], d2[3];
#pragma unroll
        for (int i = 0; i < 3; i++) { a0[i] = w0[i]; d0[i] = B0[i]; }
#pragma unroll
        for (int i = 0; i < 3; i++) {
            float za = 0.0f, zd = B1[i];
#pragma unroll
            for (int j = 0; j < 3; j++) {
                za = fmaf(w1[i * 3 + j], a0[j], za);
                zd = fmaf(w1[i * 3 + j], d0[j], zd);
            }
            a1[i] = za; d1[i] = zd;
        }
#pragma unroll
        for (int i = 0; i < 3; i++) {
            float za = 0.0f, zd = B2[i];
#pragma unroll
            for (int j = 0; j < 3; j++) {
                za = fmaf(w2[i * 3 + j], a1[j], za);
                zd = fmaf(w2[i * 3 + j], d1[j], zd);
            }
            a2[i] = za; d2[i] = zd;
        }
        float A = 0.0f, D = B3;
#pragma unroll
        for (int j = 0; j < 3; j++) {
            A = fmaf(w3[j], a2[j], A);
            D = fmaf(w3[j], d2[j], D);
        }
        sA[c]  = A;
        sDm[c] = D - 0.5f * A;
        sEA[c] = __expf(-A);
    }

    const int anyGate = __syncthreads_or(localGate);   // block-uniform

    const int tid = blockIdx.x * blockDim.x + t;
    const int stride = gridDim.x * blockDim.x;

    if (!anyGate) {
        // ---------- fast path: per-channel affine chain, float4 I/O ----------
        const int n4 = total >> 2;                 // total is a multiple of 4 here
        const int c0 = (tid << 2) & (CH - 1);      // 4 consecutive channels per thread
        float A[4], Dm[4], EA[4], K1[4], K2[4];
#pragma unroll
        for (int k = 0; k < 4; k++) {
            A[k]  = sA[c0 + k];
            Dm[k] = sDm[c0 + k];
            EA[k] = sEA[c0 + k];
            K1[k] = 1.0f - EA[k];
            K2[k] = 1.0f + EA[k];
        }
        const float4* in4    = (const float4*)in;
        const float4* noise4 = (const float4*)noise;
        float4* out4  = (float4*)out;
        float4* like4 = (float4*)(out + total);

        for (int idx = tid; idx < n4; idx += stride) {
            float4 a = in4[idx];
            float4 nz = noise4[idx];
            float v[4] = { a.x + nz.x, a.y + nz.y, a.z + nz.z, a.w + nz.w };
            out4[idx] = make_float4(v[0], v[1], v[2], v[3]);
            float lk[4];
#pragma unroll
            for (int k = 0; k < 4; k++) {
                float lo = fmaf(A[k], v[k], Dm[k]);          // lower logit
                lo = fminf(fmaxf(lo, -30.0f), 30.0f);
                float b  = __expf(-lo);                      // e^{-lo}
                // like = b*(1-EA) / (1 + b*(1+EA) + b^2*EA)
                float den = fmaf(b * EA[k], b, fmaf(b, K2[k], 1.0f));
                float lkv = (b * K1[k]) * frcp(den);
                lk[k] = fmaxf(lkv, 1e-9f);
            }
            like4[idx] = make_float4(lk[0], lk[1], lk[2], lk[3]);
        }
    } else {
        // ---------- general fallback: gated chains, scalar ----------
        const int c = tid & (CH - 1);
        float w0[3], B0[3], T0[3];
        float w1[9], B1[3], T1[3];
        float w2[9], B2[3], T2[3];
        float w3[3], B3, T3;
#pragma unroll
        for (int i = 0; i < 3; i++) {
            w0[i] = softplus_f(m0[c * 3 + i]);
            B0[i] = b0[c * 3 + i];
            T0[i] = tanhf(f0[c * 3 + i]);
            B1[i] = b1[c * 3 + i];
            T1[i] = tanhf(f1[c * 3 + i]);
            B2[i] = b2[c * 3 + i];
            T2[i] = tanhf(f2[c * 3 + i]);
            w3[i] = softplus_f(m3[c * 3 + i]);
        }
#pragma unroll
        for (int i = 0; i < 9; i++) {
            w1[i] = softplus_f(m1[c * 9 + i]);
            w2[i] = softplus_f(m2[c * 9 + i]);
        }
        B3 = b3[c];
        T3 = tanhf(f3[c]);

        for (int idx = tid; idx < total; idx += stride) {
            float v = in[idx] + noise[idx];
            out[idx] = v;
            float lo = chain_gen(v - 0.5f, w0, B0, T0, w1, B1, T1, w2, B2, T2, w3, B3, T3);
            float up = chain_gen(v + 0.5f, w0, B0, T0, w1, B1, T1, w2, B2, T2, w3, B3, T3);
            out[total + idx] = likelihood_f(lo, up);
        }
    }
}

extern "C" void kernel_launch(void* const* d_in, const int* in_sizes, int n_in,
                              void* d_out, int out_size, void* d_ws, size_t ws_size,
                              hipStream_t stream) {
    // setup_inputs() dict order: inputs, noise, m0,b0,f0, m1,b1,f1, m2,b2,f2, m3,b3,f3
    const float* in    = (const float*)d_in[0];
    const float* noise = (const float*)d_in[1];
    const float* m0 = (const float*)d_in[2];
    const float* b0 = (const float*)d_in[3];
    const float* f0 = (const float*)d_in[4];
    const float* m1 = (const float*)d_in[5];
    const float* b1 = (const float*)d_in[6];
    const float* f1 = (const float*)d_in[7];
    const float* m2 = (const float*)d_in[8];
    const float* b2 = (const float*)d_in[9];
    const float* f2 = (const float*)d_in[10];
    const float* m3 = (const float*)d_in[11];
    const float* b3 = (const float*)d_in[12];
    const float* f3 = (const float*)d_in[13];
    float* out = (float*)d_out;

    const int total = in_sizes[0];   // N*C = 32,000,000 (multiple of 4)
    const int threads = 256;
    const int blocks = 2048;

    eb_kernel<<<blocks, threads, 0, stream>>>(in, noise,
        m0, b0, f0, m1, b1, f1, m2, b2, f2, m3, b3, f3,
        out, total);
}